// Round 3
// baseline (715.846 us; speedup 1.0000x reference)
//
#include <hip/hip_runtime.h>
#include <math.h>

#define LL    1024
#define BB    16
#define NN1   2048      // 2*L
#define NNH   51200     // 50*L

__device__ __forceinline__ void fma4(float4& c, float a, const float4& w) {
    c.x = fmaf(a, w.x, c.x);
    c.y = fmaf(a, w.y, c.y);
    c.z = fmaf(a, w.z, c.z);
    c.w = fmaf(a, w.w, c.w);
}

// init accumulation targets: ypred = 0, z = b1 (bcast over batch), z2 = b2 (bcast)
__global__ void k_init(float* __restrict__ ypred, float* __restrict__ z,
                       float* __restrict__ z2,
                       const float* __restrict__ b1, const float* __restrict__ b2) {
    int i = blockIdx.x * blockDim.x + threadIdx.x;   // 0 .. BB*NNH-1 exactly
    if (i < BB * NN1) {
        ypred[i] = 0.0f;
        z2[i]    = b2[i & (NN1 - 1)];
    }
    z[i] = b1[i % NNH];
}

// K-split accumulating GEMM: out(BB,NCOL) += A(BB,KTOT)[m0:m0+CH] @ W(KTOT,NCOL)[m0:m0+CH]
// thread owns 4 consecutive columns (float4 coalesced weight stream),
// activations staged transposed in LDS and read as uniform-address (broadcast) float4.
template <int CH>
__global__ __launch_bounds__(256) void k_gemm_acc(
        const float* __restrict__ A, const float* __restrict__ W,
        float* __restrict__ out, int KTOT, int NCOL) {
    __shared__ alignas(16) float as[CH][BB];
    const int t  = threadIdx.x;
    const int n4 = blockIdx.x * 1024 + t * 4;
    const int m0 = blockIdx.y * CH;

    for (int l = t; l < CH * BB; l += 256) {
        int m = l >> 4, b = l & 15;
        as[m][b] = A[b * KTOT + m0 + m];
    }
    __syncthreads();

    float4 acc[BB];
#pragma unroll
    for (int b = 0; b < BB; ++b) acc[b] = make_float4(0.f, 0.f, 0.f, 0.f);

    const float* wp = W + (size_t)m0 * NCOL + n4;
    for (int m = 0; m < CH; ++m) {
        const float4 w = *(const float4*)wp;
        wp += NCOL;
#pragma unroll
        for (int q = 0; q < 4; ++q) {
            const float4 a = ((const float4*)as[m])[q];   // broadcast, no bank conflict
            fma4(acc[q * 4 + 0], a.x, w);
            fma4(acc[q * 4 + 1], a.y, w);
            fma4(acc[q * 4 + 2], a.z, w);
            fma4(acc[q * 4 + 3], a.w, w);
        }
    }

#pragma unroll
    for (int b = 0; b < BB; ++b) {
        float* o = out + (size_t)b * NCOL + n4;
        atomicAdd(o + 0, acc[b].x);
        atomicAdd(o + 1, acc[b].y);
        atomicAdd(o + 2, acc[b].z);
        atomicAdd(o + 3, acc[b].w);
    }
}

__global__ void k_sigmoid(float* __restrict__ z) {
    int i = blockIdx.x * blockDim.x + threadIdx.x;
    float4 v = ((float4*)z)[i];
    v.x = 1.f / (1.f + __expf(-v.x));
    v.y = 1.f / (1.f + __expf(-v.y));
    v.z = 1.f / (1.f + __expf(-v.z));
    v.w = 1.f / (1.f + __expf(-v.w));
    ((float4*)z)[i] = v;
}

// out[b,i] = (1/L) * sum_j ( yr[j]*cos(2*pi*i*j/L) - yi[j]*sin(2*pi*i*j/L) )
// == sum_j amp*cos(arg+ph) of the reference, with exact mod-L phase reduction.
__global__ __launch_bounds__(256) void k_decode(const float* __restrict__ z2,
                                                float* __restrict__ out) {
    __shared__ float yr[LL], yi[LL];
    const int t = threadIdx.x;
    const int b = blockIdx.y;
    const int i = blockIdx.x * 256 + t;
    for (int j = t; j < LL; j += 256) {
        yr[j] = z2[b * NN1 + j];
        yi[j] = z2[b * NN1 + LL + j];
    }
    __syncthreads();
    float acc = 0.f;
    int r = 0;                                // r = (i*j) mod L, exact
    for (int j = 0; j < LL; ++j) {
        float rev = (float)r * (1.0f / LL);   // revolutions in [0,1)
        float c = __builtin_amdgcn_cosf(rev); // v_cos_f32: cos(2*pi*rev)
        float s = __builtin_amdgcn_sinf(rev); // v_sin_f32: sin(2*pi*rev)
        acc = fmaf(yr[j], c, acc);
        acc = fmaf(-yi[j], s, acc);
        r = (r + i) & (LL - 1);
    }
    out[b * LL + i] = acc * (1.0f / LL);
}

extern "C" void kernel_launch(void* const* d_in, const int* in_sizes, int n_in,
                              void* d_out, int out_size, void* d_ws, size_t ws_size,
                              hipStream_t stream) {
    const float* X  = (const float*)d_in[0];
    const float* Fc = (const float*)d_in[1];
    const float* W1 = (const float*)d_in[2];
    const float* b1 = (const float*)d_in[3];
    const float* W2 = (const float*)d_in[4];
    const float* b2 = (const float*)d_in[5];
    float* out = (float*)d_out;

    float* ws    = (float*)d_ws;
    float* ypred = ws;                 // BB*NN1  = 32768 f32
    float* z     = ypred + BB * NN1;   // BB*NNH  = 819200 f32 (h in-place after sigmoid)
    float* z2    = z + BB * NNH;       // BB*NN1  = 32768 f32   (total ws: 3.54 MB)

    // init accumulators (also re-inits every call -> graph-replay safe)
    k_init<<<dim3((BB * NNH) / 256), 256, 0, stream>>>(ypred, z, z2, b1, b2);
    // y_pred = X @ Fc          : grid (2, 64),  CH=16
    k_gemm_acc<16><<<dim3(NN1 / 1024, LL / 16), 256, 0, stream>>>(X, Fc, ypred, LL, NN1);
    // z += y_pred @ W1         : grid (50, 32), CH=64   (419 MB stream)
    k_gemm_acc<64><<<dim3(NNH / 1024, NN1 / 64), 256, 0, stream>>>(ypred, W1, z, NN1, NNH);
    // h = sigmoid(z) in-place
    k_sigmoid<<<dim3((BB * NNH) / (256 * 4)), 256, 0, stream>>>(z);
    // z2 += h @ W2             : grid (2, 400), CH=128  (419 MB stream)
    k_gemm_acc<128><<<dim3(NN1 / 1024, NNH / 128), 256, 0, stream>>>(z, W2, z2, NNH, NN1);
    // decode (inverse-DFT form, exact mod-L phase)
    k_decode<<<dim3(LL / 256, BB), 256, 0, stream>>>(z2, out);
}

// Round 4
// 714.370 us; speedup vs baseline: 1.0021x; 1.0021x over previous
//
#include <hip/hip_runtime.h>
#include <math.h>

#define LL    1024
#define BB    16
#define NN1   2048      // 2*L
#define NNH   51200     // 50*L

__device__ __forceinline__ void fma4(float4& c, float a, const float4& w) {
    c.x = fmaf(a, w.x, c.x);
    c.y = fmaf(a, w.y, c.y);
    c.z = fmaf(a, w.z, c.z);
    c.w = fmaf(a, w.w, c.w);
}

// init accumulation targets: ypred = 0, z = b1 (bcast over batch), z2 = b2 (bcast)
__global__ void k_init(float* __restrict__ ypred, float* __restrict__ z,
                       float* __restrict__ z2,
                       const float* __restrict__ b1, const float* __restrict__ b2) {
    int i = blockIdx.x * blockDim.x + threadIdx.x;   // 0 .. BB*NNH-1 exactly
    if (i < BB * NN1) {
        ypred[i] = 0.0f;
        z2[i]    = b2[i & (NN1 - 1)];
    }
    z[i] = b1[i % NNH];
}

// K-split accumulating GEMM: out(BB,NCOL) += A(BB,KTOT)[m0:m0+CH] @ W(KTOT,NCOL)[m0:m0+CH]
// thread owns 4 consecutive columns (float4 coalesced weight stream),
// activations staged transposed in LDS and read as uniform-address (broadcast) float4.
template <int CH>
__global__ __launch_bounds__(256) void k_gemm_acc(
        const float* __restrict__ A, const float* __restrict__ W,
        float* __restrict__ out, int KTOT, int NCOL) {
    __shared__ alignas(16) float as[CH][BB];
    const int t  = threadIdx.x;
    const int n4 = blockIdx.x * 1024 + t * 4;
    const int m0 = blockIdx.y * CH;

    for (int l = t; l < CH * BB; l += 256) {
        int m = l >> 4, b = l & 15;
        as[m][b] = A[b * KTOT + m0 + m];
    }
    __syncthreads();

    float4 acc[BB];
#pragma unroll
    for (int b = 0; b < BB; ++b) acc[b] = make_float4(0.f, 0.f, 0.f, 0.f);

    const float* wp = W + (size_t)m0 * NCOL + n4;
    for (int m = 0; m < CH; ++m) {
        const float4 w = *(const float4*)wp;
        wp += NCOL;
#pragma unroll
        for (int q = 0; q < 4; ++q) {
            const float4 a = ((const float4*)as[m])[q];   // broadcast, no bank conflict
            fma4(acc[q * 4 + 0], a.x, w);
            fma4(acc[q * 4 + 1], a.y, w);
            fma4(acc[q * 4 + 2], a.z, w);
            fma4(acc[q * 4 + 3], a.w, w);
        }
    }

#pragma unroll
    for (int b = 0; b < BB; ++b) {
        float* o = out + (size_t)b * NCOL + n4;
        atomicAdd(o + 0, acc[b].x);
        atomicAdd(o + 1, acc[b].y);
        atomicAdd(o + 2, acc[b].z);
        atomicAdd(o + 3, acc[b].w);
    }
}

__global__ void k_sigmoid(float* __restrict__ z) {
    int i = blockIdx.x * blockDim.x + threadIdx.x;
    float4 v = ((float4*)z)[i];
    v.x = 1.f / (1.f + __expf(-v.x));
    v.y = 1.f / (1.f + __expf(-v.y));
    v.z = 1.f / (1.f + __expf(-v.z));
    v.w = 1.f / (1.f + __expf(-v.w));
    ((float4*)z)[i] = v;
}

// out[b,i] = (1/L) * sum_j ( yr[j]*cos(2*pi*i*j/L) - yi[j]*sin(2*pi*i*j/L) )
// == sum_j amp*cos(arg+ph) of the reference, with exact mod-L phase reduction.
__global__ __launch_bounds__(256) void k_decode(const float* __restrict__ z2,
                                                float* __restrict__ out) {
    __shared__ float yr[LL], yi[LL];
    const int t = threadIdx.x;
    const int b = blockIdx.y;
    const int i = blockIdx.x * 256 + t;
    for (int j = t; j < LL; j += 256) {
        yr[j] = z2[b * NN1 + j];
        yi[j] = z2[b * NN1 + LL + j];
    }
    __syncthreads();
    float acc = 0.f;
    int r = 0;                                // r = (i*j) mod L, exact
    for (int j = 0; j < LL; ++j) {
        float rev = (float)r * (1.0f / LL);   // revolutions in [0,1)
        float c = __builtin_amdgcn_cosf(rev); // v_cos_f32: cos(2*pi*rev)
        float s = __builtin_amdgcn_sinf(rev); // v_sin_f32: sin(2*pi*rev)
        acc = fmaf(yr[j], c, acc);
        acc = fmaf(-yi[j], s, acc);
        r = (r + i) & (LL - 1);
    }
    out[b * LL + i] = acc * (1.0f / LL);
}

extern "C" void kernel_launch(void* const* d_in, const int* in_sizes, int n_in,
                              void* d_out, int out_size, void* d_ws, size_t ws_size,
                              hipStream_t stream) {
    const float* X  = (const float*)d_in[0];
    const float* Fc = (const float*)d_in[1];
    const float* W1 = (const float*)d_in[2];
    const float* b1 = (const float*)d_in[3];
    const float* W2 = (const float*)d_in[4];
    const float* b2 = (const float*)d_in[5];
    float* out = (float*)d_out;

    float* ws    = (float*)d_ws;
    float* ypred = ws;                 // BB*NN1  = 32768 f32
    float* z     = ypred + BB * NN1;   // BB*NNH  = 819200 f32 (h in-place after sigmoid)
    float* z2    = z + BB * NNH;       // BB*NN1  = 32768 f32   (total ws: 3.54 MB)

    // init accumulators (also re-inits every call -> graph-replay safe)
    k_init<<<dim3((BB * NNH) / 256), 256, 0, stream>>>(ypred, z, z2, b1, b2);
    // y_pred = X @ Fc          : grid (2, 64),  CH=16
    k_gemm_acc<16><<<dim3(NN1 / 1024, LL / 16), 256, 0, stream>>>(X, Fc, ypred, LL, NN1);
    // z += y_pred @ W1         : grid (50, 32), CH=64   (419 MB stream)
    k_gemm_acc<64><<<dim3(NNH / 1024, NN1 / 64), 256, 0, stream>>>(ypred, W1, z, NN1, NNH);
    // h = sigmoid(z) in-place
    k_sigmoid<<<dim3((BB * NNH) / (256 * 4)), 256, 0, stream>>>(z);
    // z2 += h @ W2             : grid (2, 400), CH=128  (419 MB stream)
    k_gemm_acc<128><<<dim3(NN1 / 1024, NNH / 128), 256, 0, stream>>>(z, W2, z2, NNH, NN1);
    // decode (inverse-DFT form, exact mod-L phase)
    k_decode<<<dim3(LL / 256, BB), 256, 0, stream>>>(z2, out);
}

// Round 5
// 457.728 us; speedup vs baseline: 1.5639x; 1.5607x over previous
//
#include <hip/hip_runtime.h>
#include <math.h>

#define LL    1024
#define BB    16
#define NN1   2048      // 2*L
#define NNH   51200     // 50*L

__device__ __forceinline__ void fma4(float4& c, float a, const float4& w) {
    c.x = fmaf(a, w.x, c.x);
    c.y = fmaf(a, w.y, c.y);
    c.z = fmaf(a, w.z, c.z);
    c.w = fmaf(a, w.w, c.w);
}

// init accumulation targets: ypred = 0, z = b1 (bcast over batch), z2 = b2 (bcast)
__global__ void k_init(float* __restrict__ ypred, float* __restrict__ z,
                       float* __restrict__ z2,
                       const float* __restrict__ b1, const float* __restrict__ b2) {
    int i = blockIdx.x * blockDim.x + threadIdx.x;   // 0 .. BB*NNH-1 exactly
    if (i < BB * NN1) {
        ypred[i] = 0.0f;
        z2[i]    = b2[i & (NN1 - 1)];
    }
    z[i] = b1[i % NNH];
}

// K-split accumulating GEMM: out(BB,NCOL) += A(BB,KTOT)[m0:m0+CH] @ W(KTOT,NCOL)[m0:m0+CH]
// Each thread owns 4 consecutive columns x 8 batch rows (32 accumulator floats —
// fits registers; the previous 64-float version spilled to scratch at VGPR=52).
// Batch half is the LSB of blockIdx.x so the two blocks sharing a W tile are
// dispatched adjacently and the second read of the tile hits L2/L3.
template <int CH>
__global__ __launch_bounds__(256, 4) void k_gemm_acc(
        const float* __restrict__ A, const float* __restrict__ W,
        float* __restrict__ out, int KTOT, int NCOL) {
    __shared__ alignas(16) float as[CH][8];          // [m][batch row]
    const int t    = threadIdx.x;
    const int half = blockIdx.x & 1;
    const int n4   = (blockIdx.x >> 1) * 1024 + t * 4;
    const int m0   = blockIdx.y * CH;
    const int b0   = half * 8;

    for (int l = t; l < CH * 8; l += 256) {
        int m = l % CH, r = l / CH;
        as[m][r] = A[(b0 + r) * KTOT + m0 + m];
    }
    __syncthreads();

    float4 acc[8];
#pragma unroll
    for (int r = 0; r < 8; ++r) acc[r] = make_float4(0.f, 0.f, 0.f, 0.f);

    const float* wp = W + (size_t)m0 * NCOL + n4;
#pragma unroll 4
    for (int m = 0; m < CH; ++m) {
        const float4 w = *(const float4*)wp;
        wp += NCOL;
        const float4 a0 = *(const float4*)&as[m][0]; // uniform addr -> LDS broadcast
        const float4 a1 = *(const float4*)&as[m][4];
        fma4(acc[0], a0.x, w);
        fma4(acc[1], a0.y, w);
        fma4(acc[2], a0.z, w);
        fma4(acc[3], a0.w, w);
        fma4(acc[4], a1.x, w);
        fma4(acc[5], a1.y, w);
        fma4(acc[6], a1.z, w);
        fma4(acc[7], a1.w, w);
    }

#pragma unroll
    for (int r = 0; r < 8; ++r) {
        float* o = out + (size_t)(b0 + r) * NCOL + n4;
        atomicAdd(o + 0, acc[r].x);
        atomicAdd(o + 1, acc[r].y);
        atomicAdd(o + 2, acc[r].z);
        atomicAdd(o + 3, acc[r].w);
    }
}

__global__ void k_sigmoid(float* __restrict__ z) {
    int i = blockIdx.x * blockDim.x + threadIdx.x;
    float4 v = ((float4*)z)[i];
    v.x = 1.f / (1.f + __expf(-v.x));
    v.y = 1.f / (1.f + __expf(-v.y));
    v.z = 1.f / (1.f + __expf(-v.z));
    v.w = 1.f / (1.f + __expf(-v.w));
    ((float4*)z)[i] = v;
}

// out[b,i] = (1/L) * sum_j ( yr[j]*cos(2*pi*i*j/L) - yi[j]*sin(2*pi*i*j/L) )
// == sum_j amp*cos(arg+ph) of the reference, with exact mod-L phase reduction.
__global__ __launch_bounds__(256) void k_decode(const float* __restrict__ z2,
                                                float* __restrict__ out) {
    __shared__ float yr[LL], yi[LL];
    const int t = threadIdx.x;
    const int b = blockIdx.y;
    const int i = blockIdx.x * 256 + t;
    for (int j = t; j < LL; j += 256) {
        yr[j] = z2[b * NN1 + j];
        yi[j] = z2[b * NN1 + LL + j];
    }
    __syncthreads();
    float acc = 0.f;
    int r = 0;                                // r = (i*j) mod L, exact
    for (int j = 0; j < LL; ++j) {
        float rev = (float)r * (1.0f / LL);   // revolutions in [0,1)
        float c = __builtin_amdgcn_cosf(rev); // v_cos_f32: cos(2*pi*rev)
        float s = __builtin_amdgcn_sinf(rev); // v_sin_f32: sin(2*pi*rev)
        acc = fmaf(yr[j], c, acc);
        acc = fmaf(-yi[j], s, acc);
        r = (r + i) & (LL - 1);
    }
    out[b * LL + i] = acc * (1.0f / LL);
}

extern "C" void kernel_launch(void* const* d_in, const int* in_sizes, int n_in,
                              void* d_out, int out_size, void* d_ws, size_t ws_size,
                              hipStream_t stream) {
    const float* X  = (const float*)d_in[0];
    const float* Fc = (const float*)d_in[1];
    const float* W1 = (const float*)d_in[2];
    const float* b1 = (const float*)d_in[3];
    const float* W2 = (const float*)d_in[4];
    const float* b2 = (const float*)d_in[5];
    float* out = (float*)d_out;

    float* ws    = (float*)d_ws;
    float* ypred = ws;                 // BB*NN1  = 32768 f32
    float* z     = ypred + BB * NN1;   // BB*NNH  = 819200 f32 (h in-place after sigmoid)
    float* z2    = z + BB * NNH;       // BB*NN1  = 32768 f32   (total ws: 3.54 MB)

    // init accumulators (re-inits every call -> graph-replay safe)
    k_init<<<dim3((BB * NNH) / 256), 256, 0, stream>>>(ypred, z, z2, b1, b2);
    // y_pred = X @ Fc          : grid (2*2, 4)   = 16 blocks
    k_gemm_acc<256><<<dim3(2 * NN1 / 1024, LL / 256), 256, 0, stream>>>(X, Fc, ypred, LL, NN1);
    // z += y_pred @ W1         : grid (2*50, 8)  = 800 blocks  (419 MB stream)
    k_gemm_acc<256><<<dim3(2 * NNH / 1024, NN1 / 256), 256, 0, stream>>>(ypred, W1, z, NN1, NNH);
    // h = sigmoid(z) in-place
    k_sigmoid<<<dim3((BB * NNH) / (256 * 4)), 256, 0, stream>>>(z);
    // z2 += h @ W2             : grid (2*2, 200) = 800 blocks  (419 MB stream)
    k_gemm_acc<256><<<dim3(2 * NN1 / 1024, NNH / 256), 256, 0, stream>>>(z, W2, z2, NNH, NN1);
    // decode (inverse-DFT form, exact mod-L phase)
    k_decode<<<dim3(LL / 256, BB), 256, 0, stream>>>(z2, out);
}